// Round 1
// baseline (263.110 us; speedup 1.0000x reference)
//
#include <hip/hip_runtime.h>
#include <math.h>

#define BN 16
#define LC 2048
#define LQ 256
#define DD 256
#define CB 8
#define NSPLIT 16

__device__ __forceinline__ float waveReduceSum(float v) {
#pragma unroll
    for (int o = 32; o > 0; o >>= 1) v += __shfl_xor(v, o, 64);
    return v;
}
__device__ __forceinline__ float waveReduceMax(float v) {
#pragma unroll
    for (int o = 32; o > 0; o >>= 1) v = fmaxf(v, __shfl_xor(v, o, 64));
    return v;
}

// Transpose Q[n][q][d] -> QT[n][d][q], 32x32 tiles
__global__ __launch_bounds__(256) void k_transpose(const float* __restrict__ q,
                                                   float* __restrict__ qt) {
    __shared__ float tile[32][33];
    const int n = blockIdx.z;
    const int db = blockIdx.x * 32, qb = blockIdx.y * 32;
    const int tx = threadIdx.x & 31, ty = threadIdx.x >> 5;  // ty 0..7
    const float* src = q + ((size_t)(n * LQ + qb)) * DD + db;
#pragma unroll
    for (int i = 0; i < 32; i += 8) tile[ty + i][tx] = src[(size_t)(ty + i) * DD + tx];
    __syncthreads();
    float* dst = qt + ((size_t)(n * DD + db)) * LQ + qb;
#pragma unroll
    for (int i = 0; i < 32; i += 8) dst[(size_t)(ty + i) * LQ + tx] = tile[tx][ty + i];
}

// cq[n][q] = Q[n][q][:] . w_q
__global__ __launch_bounds__(64) void k_cq(const float* __restrict__ q,
                                           const float* __restrict__ W,
                                           float* __restrict__ cq) {
    const int row = blockIdx.x;  // n*LQ + q
    const int lane = threadIdx.x;
    const float* wq = W + DD;
    const float* src = q + (size_t)row * DD;
    float v = 0.f;
#pragma unroll
    for (int i = 0; i < DD; i += 64) v = fmaf(src[i + lane], wq[i + lane], v);
    v = waveReduceSum(v);
    if (lane == 0) cq[row] = v;
}

// Main fused kernel: S row block -> softmax -> c2q; writes G parts 0,1,2 and Mrow.
__global__ __launch_bounds__(256) void k_main(const float* __restrict__ ctx,
                                              const float* __restrict__ q,
                                              const float* __restrict__ qt,
                                              const float* __restrict__ cq,
                                              const float* __restrict__ W,
                                              float* __restrict__ out,
                                              float* __restrict__ Mrow) {
    __shared__ __align__(16) float sh[CB][DD];  // cm then p
    __shared__ float redA[CB][4];
    __shared__ float redB[CB][4];
    const int t = threadIdx.x;
    const int lane = t & 63, wv = t >> 6;
    const int blk = blockIdx.x;
    const int n = blk / (LC / CB);
    const int c0 = (blk % (LC / CB)) * CB;

    const float wc = W[t];
    const float wm = W[2 * DD + t];
    const float cqv = cq[n * LQ + t];

    const float* crow = ctx + ((size_t)(n * LC + c0)) * DD + t;
    float x[CB];
    float s[CB];
#pragma unroll
    for (int r = 0; r < CB; ++r) {
        x[r] = crow[(size_t)r * DD];
        sh[r][t] = x[r] * wm;
        float v = waveReduceSum(x[r] * wc);
        if (lane == 0) redA[r][wv] = v;
    }
    __syncthreads();
#pragma unroll
    for (int r = 0; r < CB; ++r)
        s[r] = redA[r][0] + redA[r][1] + redA[r][2] + redA[r][3] + cqv;

    // S accumulation: s[r] += sum_d cm[r][d] * QT[d][t]
    const float* qtn = qt + (size_t)n * DD * LQ;
    for (int d = 0; d < DD; d += 4) {
        const float q0 = qtn[(d + 0) * LQ + t];
        const float q1 = qtn[(d + 1) * LQ + t];
        const float q2 = qtn[(d + 2) * LQ + t];
        const float q3 = qtn[(d + 3) * LQ + t];
#pragma unroll
        for (int r = 0; r < CB; ++r) {
            const float4 c4 = *(const float4*)&sh[r][d];
            s[r] = fmaf(c4.x, q0, s[r]);
            s[r] = fmaf(c4.y, q1, s[r]);
            s[r] = fmaf(c4.z, q2, s[r]);
            s[r] = fmaf(c4.w, q3, s[r]);
        }
    }

    // softmax over q (across the 256 threads), per row r
    float p[CB], m[CB];
#pragma unroll
    for (int r = 0; r < CB; ++r) {
        float v = waveReduceMax(s[r]);
        if (lane == 0) redB[r][wv] = v;
    }
    __syncthreads();  // redB ready; also all sh (cm) reads done
#pragma unroll
    for (int r = 0; r < CB; ++r) {
        m[r] = fmaxf(fmaxf(redB[r][0], redB[r][1]), fmaxf(redB[r][2], redB[r][3]));
        p[r] = __expf(s[r] - m[r]);
        sh[r][t] = p[r];  // overwrite cm with unnormalized p
        float v = waveReduceSum(p[r]);
        if (lane == 0) redA[r][wv] = v;
    }
    if (t == 0) {
#pragma unroll
        for (int r = 0; r < CB; ++r) Mrow[n * LC + c0 + r] = m[r];
    }
    __syncthreads();  // p in sh, sums in redA
    float linv[CB];
#pragma unroll
    for (int r = 0; r < CB; ++r) {
        const float l = redA[r][0] + redA[r][1] + redA[r][2] + redA[r][3];
        linv[r] = 1.0f / l;
    }

    // c2q: o[r][d=t] = sum_q p[r][q] * Q[n][q][t]
    const float* qn = q + (size_t)n * LQ * DD + t;
    float o[CB] = {0, 0, 0, 0, 0, 0, 0, 0};
    for (int k = 0; k < LQ; k += 4) {
        const float a0 = qn[(size_t)(k + 0) * DD];
        const float a1 = qn[(size_t)(k + 1) * DD];
        const float a2 = qn[(size_t)(k + 2) * DD];
        const float a3 = qn[(size_t)(k + 3) * DD];
#pragma unroll
        for (int r = 0; r < CB; ++r) {
            const float4 p4 = *(const float4*)&sh[r][k];
            o[r] = fmaf(p4.x, a0, o[r]);
            o[r] = fmaf(p4.y, a1, o[r]);
            o[r] = fmaf(p4.z, a2, o[r]);
            o[r] = fmaf(p4.w, a3, o[r]);
        }
    }

    const size_t base = ((size_t)(n * LC + c0)) * 1024 + t;
#pragma unroll
    for (int r = 0; r < CB; ++r) {
        const float ov = o[r] * linv[r];
        out[base + (size_t)r * 1024] = x[r];
        out[base + (size_t)r * 1024 + 256] = ov;
        out[base + (size_t)r * 1024 + 512] = x[r] * ov;
    }
}

// bstat[n] = {max_c M, sum_c exp(M - max)}
__global__ __launch_bounds__(256) void k_bstats(const float* __restrict__ Mrow,
                                                float* __restrict__ bstat) {
    const int n = blockIdx.x, t = threadIdx.x;
    const int lane = t & 63, wv = t >> 6;
    __shared__ float red[4];
    const float* Mn = Mrow + n * LC;
    float v0[8];
    float mv = -1e30f;
#pragma unroll
    for (int i = 0; i < 8; ++i) {
        v0[i] = Mn[t + i * 256];
        mv = fmaxf(mv, v0[i]);
    }
    mv = waveReduceMax(mv);
    if (lane == 0) red[wv] = mv;
    __syncthreads();
    const float bmax = fmaxf(fmaxf(red[0], red[1]), fmaxf(red[2], red[3]));
    __syncthreads();  // before reusing red
    float sv = 0.f;
#pragma unroll
    for (int i = 0; i < 8; ++i) sv += __expf(v0[i] - bmax);
    sv = waveReduceSum(sv);
    if (lane == 0) red[wv] = sv;
    __syncthreads();
    if (t == 0) {
        bstat[2 * n] = bmax;
        bstat[2 * n + 1] = red[0] + red[1] + red[2] + red[3];
    }
}

// partial[n][s][d] = sum_{c in split s} exp(M[c]-bmax) * ctx[n][c][d]
__global__ __launch_bounds__(256) void k_q2c_partial(const float* __restrict__ ctx,
                                                     const float* __restrict__ Mrow,
                                                     const float* __restrict__ bstat,
                                                     float* __restrict__ partial) {
    const int t = threadIdx.x;
    const int n = blockIdx.y, sp = blockIdx.x;
    const int c0 = sp * (LC / NSPLIT);  // 128 rows per split
    __shared__ __align__(16) float pS[LC / NSPLIT];
    const float bmax = bstat[2 * n];
    if (t < LC / NSPLIT) pS[t] = __expf(Mrow[n * LC + c0 + t] - bmax);
    __syncthreads();
    const float* cp = ctx + ((size_t)(n * LC + c0)) * DD + t;
    float acc = 0.f;
    for (int c = 0; c < LC / NSPLIT; c += 4) {
        const float4 p4 = *(const float4*)&pS[c];
        acc = fmaf(p4.x, cp[(size_t)(c + 0) * DD], acc);
        acc = fmaf(p4.y, cp[(size_t)(c + 1) * DD], acc);
        acc = fmaf(p4.z, cp[(size_t)(c + 2) * DD], acc);
        acc = fmaf(p4.w, cp[(size_t)(c + 3) * DD], acc);
    }
    partial[((size_t)(n * NSPLIT + sp)) * DD + t] = acc;
}

__global__ __launch_bounds__(256) void k_q2c_reduce(const float* __restrict__ partial,
                                                    const float* __restrict__ bstat,
                                                    float* __restrict__ q2c) {
    const int n = blockIdx.x, t = threadIdx.x;
    float acc = 0.f;
#pragma unroll
    for (int s2 = 0; s2 < NSPLIT; ++s2) acc += partial[((size_t)(n * NSPLIT + s2)) * DD + t];
    q2c[n * DD + t] = acc / bstat[2 * n + 1];
}

// G part 3: out[n][c][768+d] = ctx[n][c][d] * q2c[n][d]
__global__ __launch_bounds__(256) void k_part4(const float* __restrict__ ctx,
                                               const float* __restrict__ q2c,
                                               float* __restrict__ out) {
    const int blk = blockIdx.x;
    const int n = blk / (LC / CB);
    const int c0 = (blk % (LC / CB)) * CB;
    const int t = threadIdx.x;
    const float g = q2c[n * DD + t];
    const float* cp = ctx + ((size_t)(n * LC + c0)) * DD + t;
    const size_t base = ((size_t)(n * LC + c0)) * 1024 + 768 + t;
#pragma unroll
    for (int r = 0; r < CB; ++r) out[base + (size_t)r * 1024] = cp[(size_t)r * DD] * g;
}

extern "C" void kernel_launch(void* const* d_in, const int* in_sizes, int n_in,
                              void* d_out, int out_size, void* d_ws, size_t ws_size,
                              hipStream_t stream) {
    const float* ctx = (const float*)d_in[0];  // (16,2048,256)
    const float* q = (const float*)d_in[1];    // (16,256,256)
    const float* W = (const float*)d_in[2];    // (768,)
    float* out = (float*)d_out;                // (16,2048,1024)

    float* ws = (float*)d_ws;
    float* qt = ws;                   // 16*256*256 = 1048576
    float* cq = qt + 1048576;         // 4096
    float* Mrow = cq + 4096;          // 32768
    float* bstat = Mrow + 32768;      // 32
    float* partial = bstat + 32;      // 16*16*256 = 65536
    float* q2c = partial + 65536;     // 4096
    // total ~4.4 MiB of d_ws

    k_transpose<<<dim3(DD / 32, LQ / 32, BN), 256, 0, stream>>>(q, qt);
    k_cq<<<BN * LQ, 64, 0, stream>>>(q, W, cq);
    k_main<<<BN * LC / CB, 256, 0, stream>>>(ctx, q, qt, cq, W, out, Mrow);
    k_bstats<<<BN, 256, 0, stream>>>(Mrow, bstat);
    k_q2c_partial<<<dim3(NSPLIT, BN), 256, 0, stream>>>(ctx, Mrow, bstat, partial);
    k_q2c_reduce<<<BN, 256, 0, stream>>>(partial, bstat, q2c);
    k_part4<<<BN * LC / CB, 256, 0, stream>>>(ctx, q2c, out);
}

// Round 2
// 92.193 us; speedup vs baseline: 2.8539x; 2.8539x over previous
//
#include <hip/hip_runtime.h>
#include <math.h>

#define BN 16
#define LC 2048
#define LQ 256
#define DD 256
#define BM 64
#define CB 8
#define NSPLIT 16

typedef _Float16 half8 __attribute__((ext_vector_type(8)));
typedef float f32x16 __attribute__((ext_vector_type(16)));

__device__ __forceinline__ float waveReduceSum(float v) {
#pragma unroll
    for (int o = 32; o > 0; o >>= 1) v += __shfl_xor(v, o, 64);
    return v;
}
__device__ __forceinline__ float waveReduceMax(float v) {
#pragma unroll
    for (int o = 32; o > 0; o >>= 1) v = fmaxf(v, __shfl_xor(v, o, 64));
    return v;
}

// Prep: Qh[n][q][d] = fp16(Q), QTh[n][d][q] = fp16(Q^T)
__global__ __launch_bounds__(256) void k_prep(const float* __restrict__ q,
                                              _Float16* __restrict__ Qh,
                                              _Float16* __restrict__ QTh) {
    __shared__ float tile[32][33];
    const int n = blockIdx.z;
    const int db = blockIdx.x * 32, qb = blockIdx.y * 32;
    const int t = threadIdx.x;
    const int tx = t & 31, ty = t >> 5;
    const float* src = q + ((size_t)(n * LQ + qb)) * DD + db;
#pragma unroll
    for (int i = 0; i < 4; ++i) {
        const int qi = ty + 8 * i;
        const float v = src[(size_t)qi * DD + tx];
        tile[qi][tx] = v;
        Qh[((size_t)(n * LQ + qb + qi)) * DD + db + tx] = (_Float16)v;
    }
    __syncthreads();
#pragma unroll
    for (int i = 0; i < 4; ++i) {
        const int di = ty + 8 * i;
        QTh[((size_t)(n * DD + db + di)) * LQ + qb + tx] = (_Float16)tile[tx][di];
    }
}

// cq[n][q] = Q[n][q][:] . w_q
__global__ __launch_bounds__(64) void k_cq(const float* __restrict__ q,
                                           const float* __restrict__ W,
                                           float* __restrict__ cq) {
    const int row = blockIdx.x;
    const int lane = threadIdx.x;
    const float* wq = W + DD;
    const float* src = q + (size_t)row * DD;
    float v = 0.f;
#pragma unroll
    for (int i = 0; i < DD; i += 64) v = fmaf(src[i + lane], wq[i + lane], v);
    v = waveReduceSum(v);
    if (lane == 0) cq[row] = v;
}

// Fused MFMA kernel: S = CM@Q^T + rowterm + colterm -> softmax -> c2q = P@Q
// Writes G parts 0,1,2 and Mrow.
__global__ __launch_bounds__(256) void k_main(const float* __restrict__ ctx,
                                              const _Float16* __restrict__ Qh,
                                              const _Float16* __restrict__ QTh,
                                              const float* __restrict__ cq,
                                              const float* __restrict__ W,
                                              float* __restrict__ out,
                                              float* __restrict__ Mrow) {
    __shared__ _Float16 Abuf[BM * 256];   // [64][256] fp16, 512B rows, XOR-swizzled
    __shared__ _Float16 Bbuf[256 * 64];   // [256][64] fp16, 128B rows, XOR-swizzled
    __shared__ float rowterm[BM];
    __shared__ float m_lds[BM];
    __shared__ float linv_lds[BM];
    __shared__ float redmax[4][BM];
    __shared__ float redsum[4][BM];

    const int t = threadIdx.x;
    const int lane = t & 63, wid = t >> 6;
    const int l31 = lane & 31, lh = lane >> 5;
    const int blk = blockIdx.x;
    const int n = blk >> 5;             // 32 blocks per batch (2048/64)
    const int c0 = (blk & 31) * BM;

    const _Float16* Qhn = Qh + (size_t)n * LQ * DD;
    const _Float16* QThn = QTh + (size_t)n * DD * LQ;

    // ---- stage one K-chunk of B: Bbuf[r][0..63] = src[r][kc*64 .. +64] ----
    auto stageB = [&](int kc, const _Float16* src) {
        const int g = t & 7;                 // 16B granule in 128B row
        const int rb = t >> 3;               // row base 0..31
#pragma unroll
        for (int i = 0; i < 8; ++i) {
            const int r = rb + 32 * i;
            const half8 v = *(const half8*)(src + (size_t)r * 256 + kc * 64 + g * 8);
            *(half8*)((char*)Bbuf + r * 128 + ((g * 16) ^ ((r & 7) << 4))) = v;
        }
    };

    stageB(0, Qhn);

    // ---- stage A = ctx*w_m (fp16) + rowterm = ctx.w_c (f32) ----
    {
        const int g = t & 31;   // 16B granule in 512B row -> cols 8g..8g+7
        const int r0 = t >> 5;  // 0..7
        float wmv[8], wcv[8];
#pragma unroll
        for (int j = 0; j < 8; ++j) {
            wmv[j] = W[2 * DD + g * 8 + j];
            wcv[j] = W[g * 8 + j];
        }
#pragma unroll
        for (int i = 0; i < 8; ++i) {
            const int r = r0 + 8 * i;
            const float* srcr = ctx + ((size_t)(n * LC + c0 + r)) * DD + g * 8;
            const float4 aa = *(const float4*)srcr;
            const float4 bb = *(const float4*)(srcr + 4);
            const float vals[8] = {aa.x, aa.y, aa.z, aa.w, bb.x, bb.y, bb.z, bb.w};
            half8 cmv;
            float rt = 0.f;
#pragma unroll
            for (int j = 0; j < 8; ++j) {
                cmv[j] = (_Float16)(vals[j] * wmv[j]);
                rt = fmaf(vals[j], wcv[j], rt);
            }
            *(half8*)((char*)Abuf + r * 512 + ((g * 16) ^ ((r & 7) << 4))) = cmv;
#pragma unroll
            for (int o = 16; o > 0; o >>= 1) rt += __shfl_xor(rt, o, 64);
            if (g == 0) rowterm[r] = rt;
        }
    }
    __syncthreads();

    // ---- GEMM1: S = CM @ Q^T ----
    f32x16 acc[2][2] = {};
    for (int kc = 0; kc < 4; ++kc) {
        if (kc > 0) {
            __syncthreads();
            stageB(kc, Qhn);
            __syncthreads();
        }
#pragma unroll
        for (int kk = 0; kk < 4; ++kk) {
            half8 af[2], bf[2];
#pragma unroll
            for (int mt = 0; mt < 2; ++mt) {
                const int row = 32 * mt + l31;
                const int kb = kc * 128 + 32 * kk + 16 * lh;
                af[mt] = *(const half8*)((const char*)Abuf + row * 512 + (kb ^ ((row & 7) << 4)));
            }
#pragma unroll
            for (int nt = 0; nt < 2; ++nt) {
                const int row = 64 * wid + 32 * nt + l31;
                const int kb = 32 * kk + 16 * lh;
                bf[nt] = *(const half8*)((const char*)Bbuf + row * 128 + (kb ^ ((row & 7) << 4)));
            }
#pragma unroll
            for (int mt = 0; mt < 2; ++mt)
#pragma unroll
                for (int nt = 0; nt < 2; ++nt)
                    acc[mt][nt] = __builtin_amdgcn_mfma_f32_32x32x16_f16(af[mt], bf[nt], acc[mt][nt], 0, 0, 0);
        }
    }
    __syncthreads();  // S1: all GEMM1 LDS reads complete

    // Stage B2 chunk 0 (Q^T-half) while softmax runs
    stageB(0, QThn);

    float cqv[2];
    cqv[0] = cq[n * LQ + 64 * wid + l31];
    cqv[1] = cq[n * LQ + 64 * wid + 32 + l31];

    // s = acc + rowterm + cq; per-row max across 256 cols
#pragma unroll
    for (int mt = 0; mt < 2; ++mt) {
#pragma unroll
        for (int r = 0; r < 16; ++r) {
            const int rl = 32 * mt + (r & 3) + 8 * (r >> 2) + 4 * lh;
            const float rterm = rowterm[rl];
            const float v0 = acc[mt][0][r] + rterm + cqv[0];
            const float v1 = acc[mt][1][r] + rterm + cqv[1];
            acc[mt][0][r] = v0;
            acc[mt][1][r] = v1;
            float mx = fmaxf(v0, v1);
#pragma unroll
            for (int o = 16; o > 0; o >>= 1) mx = fmaxf(mx, __shfl_xor(mx, o, 64));
            if (l31 == 0) redmax[wid][rl] = mx;
        }
    }
    __syncthreads();  // S2
    if (t < BM)
        m_lds[t] = fmaxf(fmaxf(redmax[0][t], redmax[1][t]), fmaxf(redmax[2][t], redmax[3][t]));
    __syncthreads();  // S3

    // p = exp(s - m); row sums; store P (unnormalized) into Abuf as fp16
#pragma unroll
    for (int mt = 0; mt < 2; ++mt) {
#pragma unroll
        for (int r = 0; r < 16; ++r) {
            const int rl = 32 * mt + (r & 3) + 8 * (r >> 2) + 4 * lh;
            const float mrow = m_lds[rl];
            const float p0 = __expf(acc[mt][0][r] - mrow);
            const float p1 = __expf(acc[mt][1][r] - mrow);
            const int q0 = 64 * wid + l31, q1 = q0 + 32;
            *((_Float16*)((char*)Abuf + rl * 512 + ((q0 * 2) ^ ((rl & 7) << 4)))) = (_Float16)p0;
            *((_Float16*)((char*)Abuf + rl * 512 + ((q1 * 2) ^ ((rl & 7) << 4)))) = (_Float16)p1;
            float sm = p0 + p1;
#pragma unroll
            for (int o = 16; o > 0; o >>= 1) sm += __shfl_xor(sm, o, 64);
            if (l31 == 0) redsum[wid][rl] = sm;
        }
    }
    __syncthreads();  // S4: P + redsum visible
    if (t < BM) {
        const float s4 = redsum[0][t] + redsum[1][t] + redsum[2][t] + redsum[3][t];
        linv_lds[t] = 1.0f / s4;
        Mrow[n * LC + c0 + t] = m_lds[t];
    }
    __syncthreads();  // S5

    // ---- GEMM2: c2q = P @ Q ----
    f32x16 acc2[2][2] = {};
    for (int kc = 0; kc < 4; ++kc) {
        if (kc > 0) {
            __syncthreads();
            stageB(kc, QThn);
            __syncthreads();
        }
#pragma unroll
        for (int kk = 0; kk < 4; ++kk) {
            half8 af[2], bf[2];
#pragma unroll
            for (int mt = 0; mt < 2; ++mt) {
                const int row = 32 * mt + l31;
                const int kb = kc * 128 + 32 * kk + 16 * lh;
                af[mt] = *(const half8*)((const char*)Abuf + row * 512 + (kb ^ ((row & 7) << 4)));
            }
#pragma unroll
            for (int nt = 0; nt < 2; ++nt) {
                const int row = 64 * wid + 32 * nt + l31;
                const int kb = 32 * kk + 16 * lh;
                bf[nt] = *(const half8*)((const char*)Bbuf + row * 128 + (kb ^ ((row & 7) << 4)));
            }
#pragma unroll
            for (int mt = 0; mt < 2; ++mt)
#pragma unroll
                for (int nt = 0; nt < 2; ++nt)
                    acc2[mt][nt] = __builtin_amdgcn_mfma_f32_32x32x16_f16(af[mt], bf[nt], acc2[mt][nt], 0, 0, 0);
        }
    }

    // ---- epilogue: G parts 0 (ctx), 1 (c2q), 2 (ctx*c2q) ----
#pragma unroll
    for (int mt = 0; mt < 2; ++mt) {
#pragma unroll
        for (int nt = 0; nt < 2; ++nt) {
            const int col = 64 * wid + 32 * nt + l31;
#pragma unroll
            for (int r = 0; r < 16; ++r) {
                const int rl = 32 * mt + (r & 3) + 8 * (r >> 2) + 4 * lh;
                const size_t gc = (size_t)(n * LC + c0 + rl);
                const float li = linv_lds[rl];
                const float ctxv = ctx[gc * DD + col];
                const float ov = acc2[mt][nt][r] * li;
                const size_t ob = gc * 1024 + col;
                out[ob] = ctxv;
                out[ob + 256] = ov;
                out[ob + 512] = ctxv * ov;
            }
        }
    }
}

// bstat[n] = {max_c M, sum_c exp(M - max)}
__global__ __launch_bounds__(256) void k_bstats(const float* __restrict__ Mrow,
                                                float* __restrict__ bstat) {
    const int n = blockIdx.x, t = threadIdx.x;
    const int lane = t & 63, wv = t >> 6;
    __shared__ float red[4];
    const float* Mn = Mrow + n * LC;
    float v0[8];
    float mv = -1e30f;
#pragma unroll
    for (int i = 0; i < 8; ++i) {
        v0[i] = Mn[t + i * 256];
        mv = fmaxf(mv, v0[i]);
    }
    mv = waveReduceMax(mv);
    if (lane == 0) red[wv] = mv;
    __syncthreads();
    const float bmax = fmaxf(fmaxf(red[0], red[1]), fmaxf(red[2], red[3]));
    __syncthreads();
    float sv = 0.f;
#pragma unroll
    for (int i = 0; i < 8; ++i) sv += __expf(v0[i] - bmax);
    sv = waveReduceSum(sv);
    if (lane == 0) red[wv] = sv;
    __syncthreads();
    if (t == 0) {
        bstat[2 * n] = bmax;
        bstat[2 * n + 1] = red[0] + red[1] + red[2] + red[3];
    }
}

__global__ __launch_bounds__(256) void k_q2c_partial(const float* __restrict__ ctx,
                                                     const float* __restrict__ Mrow,
                                                     const float* __restrict__ bstat,
                                                     float* __restrict__ partial) {
    const int t = threadIdx.x;
    const int n = blockIdx.y, sp = blockIdx.x;
    const int c0 = sp * (LC / NSPLIT);
    __shared__ __align__(16) float pS[LC / NSPLIT];
    const float bmax = bstat[2 * n];
    if (t < LC / NSPLIT) pS[t] = __expf(Mrow[n * LC + c0 + t] - bmax);
    __syncthreads();
    const float* cp = ctx + ((size_t)(n * LC + c0)) * DD + t;
    float acc = 0.f;
    for (int c = 0; c < LC / NSPLIT; c += 4) {
        const float4 p4 = *(const float4*)&pS[c];
        acc = fmaf(p4.x, cp[(size_t)(c + 0) * DD], acc);
        acc = fmaf(p4.y, cp[(size_t)(c + 1) * DD], acc);
        acc = fmaf(p4.z, cp[(size_t)(c + 2) * DD], acc);
        acc = fmaf(p4.w, cp[(size_t)(c + 3) * DD], acc);
    }
    partial[((size_t)(n * NSPLIT + sp)) * DD + t] = acc;
}

__global__ __launch_bounds__(256) void k_q2c_reduce(const float* __restrict__ partial,
                                                    const float* __restrict__ bstat,
                                                    float* __restrict__ q2c) {
    const int n = blockIdx.x, t = threadIdx.x;
    float acc = 0.f;
#pragma unroll
    for (int s2 = 0; s2 < NSPLIT; ++s2) acc += partial[((size_t)(n * NSPLIT + s2)) * DD + t];
    q2c[n * DD + t] = acc / bstat[2 * n + 1];
}

// G part 3: out[n][c][768+d] = ctx[n][c][d] * q2c[n][d]
__global__ __launch_bounds__(256) void k_part4(const float* __restrict__ ctx,
                                               const float* __restrict__ q2c,
                                               float* __restrict__ out) {
    const int blk = blockIdx.x;
    const int n = blk / (LC / CB);
    const int c0 = (blk % (LC / CB)) * CB;
    const int t = threadIdx.x;
    const float g = q2c[n * DD + t];
    const float* cp = ctx + ((size_t)(n * LC + c0)) * DD + t;
    const size_t base = ((size_t)(n * LC + c0)) * 1024 + 768 + t;
#pragma unroll
    for (int r = 0; r < CB; ++r) out[base + (size_t)r * 1024] = cp[(size_t)r * DD] * g;
}

extern "C" void kernel_launch(void* const* d_in, const int* in_sizes, int n_in,
                              void* d_out, int out_size, void* d_ws, size_t ws_size,
                              hipStream_t stream) {
    const float* ctx = (const float*)d_in[0];  // (16,2048,256)
    const float* q = (const float*)d_in[1];    // (16,256,256)
    const float* W = (const float*)d_in[2];    // (768,)
    float* out = (float*)d_out;                // (16,2048,1024)

    _Float16* Qh = (_Float16*)d_ws;                    // 16*256*256 fp16 = 2 MB
    _Float16* QTh = Qh + (size_t)BN * LQ * DD;         // 2 MB
    float* fws = (float*)(QTh + (size_t)BN * DD * LQ);
    float* cq = fws;                  // 4096
    float* Mrow = cq + BN * LQ;       // 32768
    float* bstat = Mrow + BN * LC;    // 32
    float* partial = bstat + 2 * BN;  // 65536
    float* q2c = partial + BN * NSPLIT * DD;  // 4096

    k_prep<<<dim3(8, 8, BN), 256, 0, stream>>>(q, Qh, QTh);
    k_cq<<<BN * LQ, 64, 0, stream>>>(q, W, cq);
    k_main<<<BN * LC / BM, 256, 0, stream>>>(ctx, Qh, QTh, cq, W, out, Mrow);
    k_bstats<<<BN, 256, 0, stream>>>(Mrow, bstat);
    k_q2c_partial<<<dim3(NSPLIT, BN), 256, 0, stream>>>(ctx, Mrow, bstat, partial);
    k_q2c_reduce<<<BN, 256, 0, stream>>>(partial, bstat, q2c);
    k_part4<<<BN * LC / CB, 256, 0, stream>>>(ctx, q2c, out);
}

// Round 3
// 82.384 us; speedup vs baseline: 3.1937x; 1.1191x over previous
//
#include <hip/hip_runtime.h>
#include <math.h>

#define BN 16
#define LC 2048
#define LQ 256
#define DD 256
#define BM 64

typedef _Float16 half8 __attribute__((ext_vector_type(8)));
typedef float f32x16 __attribute__((ext_vector_type(16)));

__device__ __forceinline__ float waveReduceSum(float v) {
#pragma unroll
    for (int o = 32; o > 0; o >>= 1) v += __shfl_xor(v, o, 64);
    return v;
}
__device__ __forceinline__ float waveReduceMax(float v) {
#pragma unroll
    for (int o = 32; o > 0; o >>= 1) v = fmaxf(v, __shfl_xor(v, o, 64));
    return v;
}

// Prep: Qh = fp16(Q), QTh = fp16(Q^T), cq[n][q] = Q . w_q
// grid (LQ/32, BN), 256 threads; block handles 32 q-rows x 256 d.
__global__ __launch_bounds__(256) void k_prep(const float* __restrict__ q,
                                              const float* __restrict__ W,
                                              _Float16* __restrict__ Qh,
                                              _Float16* __restrict__ QTh,
                                              float* __restrict__ cq) {
    __shared__ float tile[32][257];
    const int n = blockIdx.y;
    const int q0 = blockIdx.x * 32;
    const int t = threadIdx.x;

    // load 32 rows, cast-store Qh
#pragma unroll
    for (int i = 0; i < 32; ++i) {
        const float v = q[((size_t)(n * LQ + q0 + i)) * DD + t];
        Qh[((size_t)(n * LQ + q0 + i)) * DD + t] = (_Float16)v;
        tile[i][t] = v;
    }
    __syncthreads();

    // cq: 8 threads per row, 32 cols each
    {
        const int row = t >> 3, sub = t & 7;
        float s = 0.f;
#pragma unroll
        for (int j = 0; j < 32; ++j)
            s = fmaf(tile[row][sub * 32 + j], W[DD + sub * 32 + j], s);
        s += __shfl_xor(s, 1, 64);
        s += __shfl_xor(s, 2, 64);
        s += __shfl_xor(s, 4, 64);
        if (sub == 0) cq[n * LQ + q0 + row] = s;
    }

    // QTh: transposed write, 32x32 subtiles
    const int tx = t & 31, ty = t >> 5;
#pragma unroll
    for (int db = 0; db < 8; ++db) {
#pragma unroll
        for (int i = 0; i < 4; ++i) {
            const int d = db * 32 + ty + 8 * i;
            QTh[((size_t)(n * DD + d)) * LQ + q0 + tx] = (_Float16)tile[tx][d];
        }
    }
}

// Fused MFMA kernel: S = CM@Q^T + rowterm + colterm -> softmax -> c2q = P@Q
// Writes G parts 0,1,2 + per-block q2c partials (pq, Kb, Sb).
__global__ __launch_bounds__(256) void k_main(const float* __restrict__ ctx,
                                              const _Float16* __restrict__ Qh,
                                              const _Float16* __restrict__ QTh,
                                              const float* __restrict__ cq,
                                              const float* __restrict__ W,
                                              float* __restrict__ out,
                                              float* __restrict__ pq,
                                              float* __restrict__ KS) {
    __shared__ _Float16 Abuf[BM * 256];   // [64][256] fp16, 512B rows, XOR-swizzled
    __shared__ _Float16 Bbuf[256 * 64];   // [256][64] fp16, 128B rows, XOR-swizzled
    __shared__ float rowterm[BM];
    __shared__ float m_lds[BM];
    __shared__ float linv_lds[BM];
    __shared__ float eexp[BM];
    __shared__ float redmax[4][BM];
    __shared__ float redsum[4][BM];

    const int t = threadIdx.x;
    const int lane = t & 63, wid = t >> 6;
    const int l31 = lane & 31, lh = lane >> 5;
    const int blk = blockIdx.x;
    const int n = blk >> 5;             // 32 blocks per batch (2048/64)
    const int blk32 = blk & 31;
    const int c0 = blk32 * BM;

    const _Float16* Qhn = Qh + (size_t)n * LQ * DD;
    const _Float16* QThn = QTh + (size_t)n * DD * LQ;

    auto stageB = [&](int kc, const _Float16* src) {
        const int g = t & 7;                 // 16B granule in 128B row
        const int rb = t >> 3;               // row base 0..31
#pragma unroll
        for (int i = 0; i < 8; ++i) {
            const int r = rb + 32 * i;
            const half8 v = *(const half8*)(src + (size_t)r * 256 + kc * 64 + g * 8);
            *(half8*)((char*)Bbuf + r * 128 + ((g * 16) ^ ((r & 7) << 4))) = v;
        }
    };

    stageB(0, Qhn);

    // stage A = ctx*w_m (fp16) + rowterm = ctx.w_c (f32)
    {
        const int g = t & 31;
        const int r0 = t >> 5;
        float wmv[8], wcv[8];
#pragma unroll
        for (int j = 0; j < 8; ++j) {
            wmv[j] = W[2 * DD + g * 8 + j];
            wcv[j] = W[g * 8 + j];
        }
#pragma unroll
        for (int i = 0; i < 8; ++i) {
            const int r = r0 + 8 * i;
            const float* srcr = ctx + ((size_t)(n * LC + c0 + r)) * DD + g * 8;
            const float4 aa = *(const float4*)srcr;
            const float4 bb = *(const float4*)(srcr + 4);
            const float vals[8] = {aa.x, aa.y, aa.z, aa.w, bb.x, bb.y, bb.z, bb.w};
            half8 cmv;
            float rt = 0.f;
#pragma unroll
            for (int j = 0; j < 8; ++j) {
                cmv[j] = (_Float16)(vals[j] * wmv[j]);
                rt = fmaf(vals[j], wcv[j], rt);
            }
            *(half8*)((char*)Abuf + r * 512 + ((g * 16) ^ ((r & 7) << 4))) = cmv;
#pragma unroll
            for (int o = 16; o > 0; o >>= 1) rt += __shfl_xor(rt, o, 64);
            if (g == 0) rowterm[r] = rt;
        }
    }
    __syncthreads();

    // GEMM1: S = CM @ Q^T
    f32x16 acc[2][2] = {};
    for (int kc = 0; kc < 4; ++kc) {
        if (kc > 0) {
            __syncthreads();
            stageB(kc, Qhn);
            __syncthreads();
        }
#pragma unroll
        for (int kk = 0; kk < 4; ++kk) {
            half8 af[2], bf[2];
#pragma unroll
            for (int mt = 0; mt < 2; ++mt) {
                const int row = 32 * mt + l31;
                const int kb = kc * 128 + 32 * kk + 16 * lh;
                af[mt] = *(const half8*)((const char*)Abuf + row * 512 + (kb ^ ((row & 7) << 4)));
            }
#pragma unroll
            for (int nt = 0; nt < 2; ++nt) {
                const int row = 64 * wid + 32 * nt + l31;
                const int kb = 32 * kk + 16 * lh;
                bf[nt] = *(const half8*)((const char*)Bbuf + row * 128 + (kb ^ ((row & 7) << 4)));
            }
#pragma unroll
            for (int mt = 0; mt < 2; ++mt)
#pragma unroll
                for (int nt = 0; nt < 2; ++nt)
                    acc[mt][nt] = __builtin_amdgcn_mfma_f32_32x32x16_f16(af[mt], bf[nt], acc[mt][nt], 0, 0, 0);
        }
    }
    __syncthreads();  // S1

    stageB(0, QThn);  // prefetch GEMM2 chunk 0 during softmax

    float cqv[2];
    cqv[0] = cq[n * LQ + 64 * wid + l31];
    cqv[1] = cq[n * LQ + 64 * wid + 32 + l31];

    // s = acc + rowterm + cq; per-row max
#pragma unroll
    for (int mt = 0; mt < 2; ++mt) {
#pragma unroll
        for (int r = 0; r < 16; ++r) {
            const int rl = 32 * mt + (r & 3) + 8 * (r >> 2) + 4 * lh;
            const float rterm = rowterm[rl];
            const float v0 = acc[mt][0][r] + rterm + cqv[0];
            const float v1 = acc[mt][1][r] + rterm + cqv[1];
            acc[mt][0][r] = v0;
            acc[mt][1][r] = v1;
            float mx = fmaxf(v0, v1);
#pragma unroll
            for (int o = 16; o > 0; o >>= 1) mx = fmaxf(mx, __shfl_xor(mx, o, 64));
            if (l31 == 0) redmax[wid][rl] = mx;
        }
    }
    __syncthreads();  // S2
    if (t < BM)
        m_lds[t] = fmaxf(fmaxf(redmax[0][t], redmax[1][t]), fmaxf(redmax[2][t], redmax[3][t]));
    __syncthreads();  // S3

    // wave 0: q2c partial stats (Kb, Sb, eexp[r] = exp(m[r]-Kb))
    if (t < BM) {
        const float mv = m_lds[t];
        const float kb = waveReduceMax(mv);
        const float e = __expf(mv - kb);
        eexp[t] = e;
        const float sb = waveReduceSum(e);
        if (t == 0) {
            KS[(n * 32 + blk32) * 2 + 0] = kb;
            KS[(n * 32 + blk32) * 2 + 1] = sb;
        }
    }

    // p = exp(s - m); row sums; store P (unnormalized fp16) into Abuf
#pragma unroll
    for (int mt = 0; mt < 2; ++mt) {
#pragma unroll
        for (int r = 0; r < 16; ++r) {
            const int rl = 32 * mt + (r & 3) + 8 * (r >> 2) + 4 * lh;
            const float mrow = m_lds[rl];
            const float p0 = __expf(acc[mt][0][r] - mrow);
            const float p1 = __expf(acc[mt][1][r] - mrow);
            const int q0 = 64 * wid + l31, q1 = q0 + 32;
            *((_Float16*)((char*)Abuf + rl * 512 + ((q0 * 2) ^ ((rl & 7) << 4)))) = (_Float16)p0;
            *((_Float16*)((char*)Abuf + rl * 512 + ((q1 * 2) ^ ((rl & 7) << 4)))) = (_Float16)p1;
            float sm = p0 + p1;
#pragma unroll
            for (int o = 16; o > 0; o >>= 1) sm += __shfl_xor(sm, o, 64);
            if (l31 == 0) redsum[wid][rl] = sm;
        }
    }
    __syncthreads();  // S4
    if (t < BM) {
        const float s4 = redsum[0][t] + redsum[1][t] + redsum[2][t] + redsum[3][t];
        linv_lds[t] = 1.0f / s4;
    }
    __syncthreads();  // S5

    // GEMM2: c2q = P @ Q
    f32x16 acc2[2][2] = {};
    for (int kc = 0; kc < 4; ++kc) {
        if (kc > 0) {
            __syncthreads();
            stageB(kc, QThn);
            __syncthreads();
        }
#pragma unroll
        for (int kk = 0; kk < 4; ++kk) {
            half8 af[2], bf[2];
#pragma unroll
            for (int mt = 0; mt < 2; ++mt) {
                const int row = 32 * mt + l31;
                const int kb = kc * 128 + 32 * kk + 16 * lh;
                af[mt] = *(const half8*)((const char*)Abuf + row * 512 + (kb ^ ((row & 7) << 4)));
            }
#pragma unroll
            for (int nt = 0; nt < 2; ++nt) {
                const int row = 64 * wid + 32 * nt + l31;
                const int kb = 32 * kk + 16 * lh;
                bf[nt] = *(const half8*)((const char*)Bbuf + row * 128 + (kb ^ ((row & 7) << 4)));
            }
#pragma unroll
            for (int mt = 0; mt < 2; ++mt)
#pragma unroll
                for (int nt = 0; nt < 2; ++nt)
                    acc2[mt][nt] = __builtin_amdgcn_mfma_f32_32x32x16_f16(af[mt], bf[nt], acc2[mt][nt], 0, 0, 0);
        }
    }

    // epilogue: G parts 0,1,2 + q2c partial accumulation
    float pqa[2] = {0.f, 0.f};
#pragma unroll
    for (int mt = 0; mt < 2; ++mt) {
#pragma unroll
        for (int nt = 0; nt < 2; ++nt) {
            const int col = 64 * wid + 32 * nt + l31;
#pragma unroll
            for (int r = 0; r < 16; ++r) {
                const int rl = 32 * mt + (r & 3) + 8 * (r >> 2) + 4 * lh;
                const size_t gc = (size_t)(n * LC + c0 + rl);
                const float li = linv_lds[rl];
                const float ctxv = ctx[gc * DD + col];
                const float ov = acc2[mt][nt][r] * li;
                const size_t ob = gc * 1024 + col;
                out[ob] = ctxv;
                out[ob + 256] = ov;
                out[ob + 512] = ctxv * ov;
                pqa[nt] = fmaf(eexp[rl], ctxv, pqa[nt]);
            }
        }
    }
#pragma unroll
    for (int nt = 0; nt < 2; ++nt) {
        pqa[nt] += __shfl_xor(pqa[nt], 32, 64);
        if (lh == 0) {
            const int col = 64 * wid + 32 * nt + l31;
            pq[((size_t)(n * 32 + blk32)) * 256 + col] = pqa[nt];
        }
    }
}

// Tail: combine per-block partials -> q2c, write G part 3.
__global__ __launch_bounds__(256) void k_tail(const float* __restrict__ ctx,
                                              const float* __restrict__ pq,
                                              const float* __restrict__ KS,
                                              float* __restrict__ out) {
    const int blk = blockIdx.x;
    const int n = blk >> 5;
    const int c0 = (blk & 31) * BM;
    const int t = threadIdx.x;

    float bmax = -1e30f;
#pragma unroll
    for (int b = 0; b < 32; ++b) bmax = fmaxf(bmax, KS[(n * 32 + b) * 2]);
    float Z = 0.f;
    float acc = 0.f;
#pragma unroll
    for (int b = 0; b < 32; ++b) {
        const float w = __expf(KS[(n * 32 + b) * 2] - bmax);
        Z = fmaf(w, KS[(n * 32 + b) * 2 + 1], Z);
        acc = fmaf(w, pq[((size_t)(n * 32 + b)) * 256 + t], acc);
    }
    const float q2cd = acc / Z;

#pragma unroll 4
    for (int r = 0; r < BM; ++r) {
        const size_t gc = (size_t)(n * LC + c0 + r);
        out[gc * 1024 + 768 + t] = ctx[gc * DD + t] * q2cd;
    }
}

extern "C" void kernel_launch(void* const* d_in, const int* in_sizes, int n_in,
                              void* d_out, int out_size, void* d_ws, size_t ws_size,
                              hipStream_t stream) {
    const float* ctx = (const float*)d_in[0];  // (16,2048,256)
    const float* q = (const float*)d_in[1];    // (16,256,256)
    const float* W = (const float*)d_in[2];    // (768,)
    float* out = (float*)d_out;                // (16,2048,1024)

    _Float16* Qh = (_Float16*)d_ws;                    // 2 MB
    _Float16* QTh = Qh + (size_t)BN * LQ * DD;         // 2 MB
    float* fws = (float*)(QTh + (size_t)BN * DD * LQ);
    float* cq = fws;                  // 4096
    float* pq = cq + BN * LQ;         // 16*32*256 = 131072
    float* KS = pq + BN * 32 * 256;   // 1024

    k_prep<<<dim3(LQ / 32, BN), 256, 0, stream>>>(q, W, Qh, QTh, cq);
    k_main<<<BN * LC / BM, 256, 0, stream>>>(ctx, Qh, QTh, cq, W, out, pq, KS);
    k_tail<<<BN * LC / BM, 256, 0, stream>>>(ctx, pq, KS, out);
}

// Round 4
// 70.639 us; speedup vs baseline: 3.7247x; 1.1663x over previous
//
#include <hip/hip_runtime.h>
#include <math.h>

#define BN 16
#define LC 2048
#define LQ 256
#define DD 256
#define BM 128
#define NT 512

typedef _Float16 half8 __attribute__((ext_vector_type(8)));
typedef float f32x16 __attribute__((ext_vector_type(16)));

typedef const __attribute__((address_space(1))) void* gas_p;
typedef __attribute__((address_space(3))) void* lds_p;
#define GLOAD_LDS16(gp, lp) \
    __builtin_amdgcn_global_load_lds((gas_p)(gp), (lds_p)(lp), 16, 0, 0)

__device__ __forceinline__ float waveReduceSum(float v) {
#pragma unroll
    for (int o = 32; o > 0; o >>= 1) v += __shfl_xor(v, o, 64);
    return v;
}
__device__ __forceinline__ float waveReduceMax(float v) {
#pragma unroll
    for (int o = 32; o > 0; o >>= 1) v = fmaxf(v, __shfl_xor(v, o, 64));
    return v;
}

// Prep: Qh = fp16(Q), QTh = fp16(Q^T), cq[n][q] = Q . w_q
__global__ __launch_bounds__(256) void k_prep(const float* __restrict__ q,
                                              const float* __restrict__ W,
                                              _Float16* __restrict__ Qh,
                                              _Float16* __restrict__ QTh,
                                              float* __restrict__ cq) {
    __shared__ float tile[32][257];
    const int n = blockIdx.y;
    const int q0 = blockIdx.x * 32;
    const int t = threadIdx.x;

#pragma unroll
    for (int i = 0; i < 32; ++i) {
        const float v = q[((size_t)(n * LQ + q0 + i)) * DD + t];
        Qh[((size_t)(n * LQ + q0 + i)) * DD + t] = (_Float16)v;
        tile[i][t] = v;
    }
    __syncthreads();

    {
        const int row = t >> 3, sub = t & 7;
        float s = 0.f;
#pragma unroll
        for (int j = 0; j < 32; ++j)
            s = fmaf(tile[row][sub * 32 + j], W[DD + sub * 32 + j], s);
        s += __shfl_xor(s, 1, 64);
        s += __shfl_xor(s, 2, 64);
        s += __shfl_xor(s, 4, 64);
        if (sub == 0) cq[n * LQ + q0 + row] = s;
    }

    const int tx = t & 31, ty = t >> 5;
#pragma unroll
    for (int db = 0; db < 8; ++db) {
#pragma unroll
        for (int i = 0; i < 4; ++i) {
            const int d = db * 32 + ty + 8 * i;
            QTh[((size_t)(n * DD + d)) * LQ + q0 + tx] = (_Float16)tile[tx][d];
        }
    }
}

// Fused MFMA kernel, BM=128 rows/block, 8 waves (2 row-halves x 4 col-quarters),
// double-buffered async B staging via global_load_lds (pre-swizzled source).
__global__ __launch_bounds__(NT) void k_main(const float* __restrict__ ctx,
                                             const _Float16* __restrict__ Qh,
                                             const _Float16* __restrict__ QTh,
                                             const float* __restrict__ cq,
                                             const float* __restrict__ W,
                                             float* __restrict__ out,
                                             float* __restrict__ pq,
                                             float* __restrict__ KS) {
    __shared__ _Float16 Abuf[BM * 256];     // 64KB, 512B rows, XOR-swizzled
    __shared__ _Float16 Bbuf[2][256 * 64];  // 2 x 32KB, 128B rows, XOR-swizzled
    __shared__ float rowterm[BM];
    __shared__ float m_lds[BM];
    __shared__ float linv_lds[BM];
    __shared__ float eexp[BM];
    __shared__ float redmax[4][BM];
    __shared__ float redsum[4][BM];

    const int t = threadIdx.x;
    const int lane = t & 63, wid = t >> 6;
    const int l31 = lane & 31, lh = lane >> 5;
    const int wr = wid >> 2, wc = wid & 3;
    const int blk = blockIdx.x;
    const int n = blk >> 4;   // 16 blocks per batch
    const int blk16 = blk & 15;
    const int c0 = blk16 * BM;

    const _Float16* Qhn = Qh + (size_t)n * LQ * DD;
    const _Float16* QThn = QTh + (size_t)n * DD * LQ;

    // Stage B chunk kc (32KB: 256 rows x 64 halfs) into Bbuf[buf].
    // LDS dest linear (base + lane*16); source col-granule pre-swizzled by r&7.
    auto stageB = [&](int kc, const _Float16* src, int buf) {
#pragma unroll
        for (int j = 0; j < 4; ++j) {
            const int r = wid * 32 + j * 8 + (lane >> 3);
            const int gs = (lane & 7) ^ (r & 7);
            const _Float16* gp = src + (size_t)r * 256 + kc * 64 + gs * 8;
            _Float16* lp = &Bbuf[buf][(wid * 32 + j * 8) * 64];
            GLOAD_LDS16(gp, lp);
        }
    };

    auto gemmChunk = [&](f32x16 (&acc)[2][2], int kcA, int buf) {
#pragma unroll
        for (int kk = 0; kk < 4; ++kk) {
            half8 af[2], bf[2];
#pragma unroll
            for (int mt = 0; mt < 2; ++mt) {
                const int row = 64 * wr + 32 * mt + l31;
                const int kb = kcA * 128 + 32 * kk + 16 * lh;
                af[mt] = *(const half8*)((const char*)Abuf + row * 512 + (kb ^ ((row & 7) << 4)));
            }
#pragma unroll
            for (int nt = 0; nt < 2; ++nt) {
                const int row = 64 * wc + 32 * nt + l31;
                const int kb = 32 * kk + 16 * lh;
                bf[nt] = *(const half8*)((const char*)Bbuf[buf] + row * 128 + (kb ^ ((row & 7) << 4)));
            }
#pragma unroll
            for (int mt = 0; mt < 2; ++mt)
#pragma unroll
                for (int nt = 0; nt < 2; ++nt)
                    acc[mt][nt] = __builtin_amdgcn_mfma_f32_32x32x16_f16(af[mt], bf[nt], acc[mt][nt], 0, 0, 0);
        }
    };

    stageB(0, Qhn, 0);  // async, in flight under A-stage

    // Stage A = ctx*w_m (fp16, swizzled) + rowterm = ctx.w_c
    {
        const int g = t & 31;    // col granule (8 floats)
        const int r0 = t >> 5;   // 0..15
        float wmv[8], wcv[8];
#pragma unroll
        for (int j = 0; j < 8; ++j) {
            wmv[j] = W[2 * DD + g * 8 + j];
            wcv[j] = W[g * 8 + j];
        }
#pragma unroll
        for (int i = 0; i < 8; ++i) {
            const int r = r0 + 16 * i;
            const float* srcr = ctx + ((size_t)(n * LC + c0 + r)) * DD + g * 8;
            const float4 aa = *(const float4*)srcr;
            const float4 bb = *(const float4*)(srcr + 4);
            const float vals[8] = {aa.x, aa.y, aa.z, aa.w, bb.x, bb.y, bb.z, bb.w};
            half8 cmv;
            float rt = 0.f;
#pragma unroll
            for (int j = 0; j < 8; ++j) {
                cmv[j] = (_Float16)(vals[j] * wmv[j]);
                rt = fmaf(vals[j], wcv[j], rt);
            }
            *(half8*)((char*)Abuf + r * 512 + ((g * 16) ^ ((r & 7) << 4))) = cmv;
#pragma unroll
            for (int o = 16; o > 0; o >>= 1) rt += __shfl_xor(rt, o, 64);
            if (g == 0) rowterm[r] = rt;
        }
    }
    __syncthreads();  // A + B0 ready

    // GEMM1: S = CM @ Q^T  (B rows = q, K = d)
    f32x16 acc[2][2] = {};
#pragma unroll
    for (int kc = 0; kc < 4; ++kc) {
        if (kc) __syncthreads();
        if (kc < 3) stageB(kc + 1, Qhn, (kc + 1) & 1);
        else stageB(0, QThn, 0);  // prefetch GEMM2 chunk 0
        gemmChunk(acc, kc, kc & 1);
    }
    __syncthreads();  // S1: GEMM1 done, QT0 staged in buf0

    float cqv[2];
    cqv[0] = cq[n * LQ + 64 * wc + l31];
    cqv[1] = cq[n * LQ + 64 * wc + 32 + l31];

    // s = acc + rowterm + cq; per-row max
#pragma unroll
    for (int mt = 0; mt < 2; ++mt) {
#pragma unroll
        for (int r = 0; r < 16; ++r) {
            const int rl = 64 * wr + 32 * mt + (r & 3) + 8 * (r >> 2) + 4 * lh;
            const float rterm = rowterm[rl];
            const float v0 = acc[mt][0][r] + rterm + cqv[0];
            const float v1 = acc[mt][1][r] + rterm + cqv[1];
            acc[mt][0][r] = v0;
            acc[mt][1][r] = v1;
            float mx = fmaxf(v0, v1);
#pragma unroll
            for (int o = 16; o > 0; o >>= 1) mx = fmaxf(mx, __shfl_xor(mx, o, 64));
            if (l31 == 0) redmax[wc][rl] = mx;
        }
    }
    __syncthreads();  // S2
    if (t < BM)
        m_lds[t] = fmaxf(fmaxf(redmax[0][t], redmax[1][t]), fmaxf(redmax[2][t], redmax[3][t]));
    __syncthreads();  // S3

    // waves 0,1: per-64-row q2c partial stats
    if (t < BM) {
        const float mv = m_lds[t];
        const float kb = waveReduceMax(mv);
        const float e = __expf(mv - kb);
        eexp[t] = e;
        const float sb = waveReduceSum(e);
        if (lane == 0) {
            KS[(n * 32 + blk16 * 2 + (t >> 6)) * 2 + 0] = kb;
            KS[(n * 32 + blk16 * 2 + (t >> 6)) * 2 + 1] = sb;
        }
    }

    // p = exp(s - m); row sums; store P (unnormalized fp16) into Abuf
#pragma unroll
    for (int mt = 0; mt < 2; ++mt) {
#pragma unroll
        for (int r = 0; r < 16; ++r) {
            const int rl = 64 * wr + 32 * mt + (r & 3) + 8 * (r >> 2) + 4 * lh;
            const float mrow = m_lds[rl];
            const float p0 = __expf(acc[mt][0][r] - mrow);
            const float p1 = __expf(acc[mt][1][r] - mrow);
            const int q0 = 64 * wc + l31, q1 = q0 + 32;
            *((_Float16*)((char*)Abuf + rl * 512 + ((q0 * 2) ^ ((rl & 7) << 4)))) = (_Float16)p0;
            *((_Float16*)((char*)Abuf + rl * 512 + ((q1 * 2) ^ ((rl & 7) << 4)))) = (_Float16)p1;
            float sm = p0 + p1;
#pragma unroll
            for (int o = 16; o > 0; o >>= 1) sm += __shfl_xor(sm, o, 64);
            if (l31 == 0) redsum[wc][rl] = sm;
        }
    }
    __syncthreads();  // S4
    if (t < BM)
        linv_lds[t] = 1.0f / (redsum[0][t] + redsum[1][t] + redsum[2][t] + redsum[3][t]);
    __syncthreads();  // S5

    // GEMM2: c2q = P @ Q  (B rows = d via QT, K = q)
    f32x16 acc2[2][2] = {};
#pragma unroll
    for (int kc = 0; kc < 4; ++kc) {
        if (kc) __syncthreads();
        if (kc < 3) stageB(kc + 1, QThn, (kc + 1) & 1);
        gemmChunk(acc2, kc, kc & 1);
    }

    // epilogue: G parts 0,1,2 + q2c partial accumulation
    float pqa[2] = {0.f, 0.f};
#pragma unroll
    for (int mt = 0; mt < 2; ++mt) {
#pragma unroll
        for (int nt = 0; nt < 2; ++nt) {
            const int col = 64 * wc + 32 * nt + l31;
#pragma unroll
            for (int r = 0; r < 16; ++r) {
                const int rl = 64 * wr + 32 * mt + (r & 3) + 8 * (r >> 2) + 4 * lh;
                const size_t gc = (size_t)(n * LC + c0 + rl);
                const float li = linv_lds[rl];
                const float ctxv = ctx[gc * DD + col];
                const float ov = acc2[mt][nt][r] * li;
                const size_t ob = gc * 1024 + col;
                out[ob] = ctxv;
                out[ob + 256] = ov;
                out[ob + 512] = ctxv * ov;
                pqa[nt] = fmaf(eexp[rl], ctxv, pqa[nt]);
            }
        }
    }
#pragma unroll
    for (int nt = 0; nt < 2; ++nt) {
        pqa[nt] += __shfl_xor(pqa[nt], 32, 64);
        if (lh == 0) {
            const int col = 64 * wc + 32 * nt + l31;
            pq[((size_t)(n * 32 + blk16 * 2 + wr)) * 256 + col] = pqa[nt];
        }
    }
}

// Tail: combine per-64-row partials -> q2c, write G part 3. 64 rows per block.
__global__ __launch_bounds__(256) void k_tail(const float* __restrict__ ctx,
                                              const float* __restrict__ pq,
                                              const float* __restrict__ KS,
                                              float* __restrict__ out) {
    const int blk = blockIdx.x;
    const int n = blk >> 5;
    const int c0 = (blk & 31) * 64;
    const int t = threadIdx.x;

    float bmax = -1e30f;
#pragma unroll
    for (int b = 0; b < 32; ++b) bmax = fmaxf(bmax, KS[(n * 32 + b) * 2]);
    float Z = 0.f;
    float acc = 0.f;
#pragma unroll
    for (int b = 0; b < 32; ++b) {
        const float w = __expf(KS[(n * 32 + b) * 2] - bmax);
        Z = fmaf(w, KS[(n * 32 + b) * 2 + 1], Z);
        acc = fmaf(w, pq[((size_t)(n * 32 + b)) * 256 + t], acc);
    }
    const float q2cd = acc / Z;

#pragma unroll 4
    for (int r = 0; r < 64; ++r) {
        const size_t gc = (size_t)(n * LC + c0 + r);
        out[gc * 1024 + 768 + t] = ctx[gc * DD + t] * q2cd;
    }
}

extern "C" void kernel_launch(void* const* d_in, const int* in_sizes, int n_in,
                              void* d_out, int out_size, void* d_ws, size_t ws_size,
                              hipStream_t stream) {
    const float* ctx = (const float*)d_in[0];  // (16,2048,256)
    const float* q = (const float*)d_in[1];    // (16,256,256)
    const float* W = (const float*)d_in[2];    // (768,)
    float* out = (float*)d_out;                // (16,2048,1024)

    _Float16* Qh = (_Float16*)d_ws;                    // 2 MB
    _Float16* QTh = Qh + (size_t)BN * LQ * DD;         // 2 MB
    float* fws = (float*)(QTh + (size_t)BN * DD * LQ);
    float* cq = fws;                  // 4096
    float* pq = cq + BN * LQ;         // 16*32*256 = 131072
    float* KS = pq + BN * 32 * 256;   // 1024

    k_prep<<<dim3(LQ / 32, BN), 256, 0, stream>>>(q, W, Qh, QTh, cq);
    k_main<<<BN * LC / BM, NT, 0, stream>>>(ctx, Qh, QTh, cq, W, out, pq, KS);
    k_tail<<<BN * LC / 64, 256, 0, stream>>>(ctx, pq, KS, out);
}